// Round 12
// baseline (249.489 us; speedup 1.0000x reference)
//
#include <hip/hip_runtime.h>
#include <hip/hip_bf16.h>

#define N_NODES 50000
#define K_NB 16
#define E_EDGES 800000
#define B_MOL 1024
#define MAXM_M 48
#define FDIM 9
#define ADIM 10
#define H 64
#define NEG_INF_F (-1e9f)
#define PRE_NODE_BLOCKS 196  /* 1 thread per node */
#define EDGE_BLOCKS 3125     /* 256 edges per block */

__device__ inline float readlane_f(float v, int l) {
    return __int_as_float(__builtin_amdgcn_readlane(__float_as_int(v), l));
}
__device__ inline int readlane_i(int v, int l) {
    return __builtin_amdgcn_readlane(v, l);
}
__device__ inline unsigned readlane_u(unsigned v, int l) {
    return (unsigned)__builtin_amdgcn_readlane((int)v, l);
}
__device__ inline float bf2f(unsigned u) {         // u = zero-extended bf16
    return __uint_as_float(u << 16);
}
__device__ inline float bf2f_lo(unsigned u) { return __uint_as_float(u << 16); }
__device__ inline float bf2f_hi(unsigned u) { return __uint_as_float(u & 0xffff0000u); }
__device__ inline unsigned short f2bf(float f) {   // round-to-nearest-even
    unsigned x = __float_as_uint(f);
    return (unsigned short)((x + 0x7fffu + ((x >> 16) & 1u)) >> 16);
}

// Raw gather, wave-uniform SGPR base + per-lane VGPR byte offset.
#define GLOAD_U16(dst, voff, sbase) \
    asm volatile("global_load_ushort %0, %1, %2" : "=v"(dst) : "v"(voff), "s"(sbase))
#define GLOAD_F32(dst, voff, sbase) \
    asm volatile("global_load_dword %0, %1, %2" : "=v"(dst) : "v"(voff), "s"(sbase))
// Raw gather, fully per-lane 64-bit address.
#define GLOADP_U16(dst, ptr) \
    asm volatile("global_load_ushort %0, %1, off" : "=v"(dst) : "v"(ptr))

#define DRAIN16(a) \
    asm volatile("s_waitcnt vmcnt(0)" \
        : "+v"(a[0]), "+v"(a[1]), "+v"(a[2]), "+v"(a[3]), \
          "+v"(a[4]), "+v"(a[5]), "+v"(a[6]), "+v"(a[7]), \
          "+v"(a[8]), "+v"(a[9]), "+v"(a[10]), "+v"(a[11]), \
          "+v"(a[12]), "+v"(a[13]), "+v"(a[14]), "+v"(a[15]))
#define HOLD16(a) \
    asm volatile("" \
        : "+v"(a[0]), "+v"(a[1]), "+v"(a[2]), "+v"(a[3]), \
          "+v"(a[4]), "+v"(a[5]), "+v"(a[6]), "+v"(a[7]), \
          "+v"(a[8]), "+v"(a[9]), "+v"(a[10]), "+v"(a[11]), \
          "+v"(a[12]), "+v"(a[13]), "+v"(a[14]), "+v"(a[15]))

// ---------------------------------------------------------------------------
// Fold all weight algebra (single block, LDS-staged).
// ---------------------------------------------------------------------------
__global__ __launch_bounds__(256) void k_fold(
    const float* __restrict__ W_emb, const float* __restrict__ b_emb,
    const float* __restrict__ W_dist, const float* __restrict__ b_dist,
    const float* __restrict__ W_gat, const float* __restrict__ Wm_gat,
    const float* __restrict__ a_gat,
    float* __restrict__ W2, float* __restrict__ c2,
    float* __restrict__ W3, float* __restrict__ c3,
    float* __restrict__ wa, float* __restrict__ ca,
    float* __restrict__ va, float* __restrict__ vb,
    float* __restrict__ wv9, float* __restrict__ cv)
{
    __shared__ float s_va[64], s_vb[64];
    int tid = threadIdx.x;
    int h = tid & 63, g = tid >> 6;
    if (g == 0) {            // va[h] = W_gat[h,:] . a1
        float acc = 0.f;
        for (int t = 0; t < H; ++t) acc += W_gat[h * H + t] * a_gat[t];
        s_va[h] = acc; va[h] = acc;
    } else if (g == 1) {     // vb[h] = Wm_gat[h,:] . a2
        float acc = 0.f;
        for (int t = 0; t < H; ++t) acc += Wm_gat[h * H + t] * a_gat[H + t];
        s_vb[h] = acc; vb[h] = acc;
    } else if (g == 2) {     // c2
        float acc = 0.f;
        for (int t = 0; t < H; ++t) acc += b_dist[t] * Wm_gat[t * H + h];
        c2[h] = acc;
    } else {                 // c3
        float acc = 0.f;
        for (int t = 0; t < H; ++t) acc += b_emb[t] * W_gat[t * H + h];
        c3[h] = acc;
    }
    __syncthreads();
    for (int q = tid; q < 640; q += 256) {   // W2[j,h]
        int j = q >> 6, hh = q & 63;
        float acc = 0.f;
        for (int t = 0; t < H; ++t) acc += W_dist[j * H + t] * Wm_gat[t * H + hh];
        W2[q] = acc;
    }
    for (int q = tid; q < 576; q += 256) {   // W3[j,h]
        int j = q >> 6, hh = q & 63;
        float acc = 0.f;
        for (int t = 0; t < H; ++t) acc += W_emb[j * H + t] * W_gat[t * H + hh];
        W3[q] = acc;
    }
    if (tid < ADIM) {                         // wa
        float acc = 0.f;
        for (int t = 0; t < H; ++t) acc += W_dist[tid * H + t] * s_vb[t];
        wa[tid] = acc;
    } else if (tid == ADIM) {                 // ca
        float acc = 0.f;
        for (int t = 0; t < H; ++t) acc += b_dist[t] * s_vb[t];
        ca[0] = acc;
    } else if (tid >= 16 && tid < 16 + FDIM) {// wv9
        int j = tid - 16;
        float acc = 0.f;
        for (int t = 0; t < H; ++t) acc += W_emb[j * H + t] * s_va[t];
        wv9[j] = acc;
    } else if (tid == 31) {                   // cv
        float acc = 0.f;
        for (int t = 0; t < H; ++t) acc += b_emb[t] * s_va[t];
        cv[0] = acc;
    }
}

// ---------------------------------------------------------------------------
// Pre-pass: t1A + tfp records (node side); emsg records + sue (edge side).
// ---------------------------------------------------------------------------
__global__ __launch_bounds__(256) void k_pre(
    const float* __restrict__ tf, const float* __restrict__ fdg,
    const float* __restrict__ rij,
    const int* __restrict__ su, const int* __restrict__ sul,
    const float* __restrict__ wa, const float* __restrict__ ca,
    const float* __restrict__ wv9, const float* __restrict__ cv,
    float* __restrict__ t1A, unsigned short* __restrict__ tfp,
    unsigned short* __restrict__ emsg, int* __restrict__ sue)
{
    int bid = blockIdx.x;
    if (bid < PRE_NODE_BLOCKS) {
        int n = bid * 256 + threadIdx.x;
        if (n == 0) {                        // zero pad row
            t1A[0] = 0.f;
            uint4 z = make_uint4(0, 0, 0, 0);
            ((uint4*)tfp)[0] = z; ((uint4*)tfp)[1] = z;
        }
        if (n >= N_NODES) return;
        float f[FDIM];
        float acc = cv[0];
#pragma unroll
        for (int j = 0; j < FDIM; ++j) {
            f[j] = tf[n * FDIM + j];
            acc += f[j] * wv9[j];
        }
        t1A[n + 1] = acc;
        unsigned rec[8];
#pragma unroll
        for (int j = 0; j < 4; ++j)
            rec[j] = (unsigned)f2bf(f[2 * j]) | ((unsigned)f2bf(f[2 * j + 1]) << 16);
        rec[4] = (unsigned)f2bf(f[8]);
        rec[5] = 0; rec[6] = 0; rec[7] = 0;
        uint4* dst = (uint4*)(tfp + (size_t)(n + 1) * 16);
        dst[0] = make_uint4(rec[0], rec[1], rec[2], rec[3]);
        dst[1] = make_uint4(rec[4], rec[5], rec[6], rec[7]);
    } else {
        int e = (bid - PRE_NODE_BLOCKS) * 256 + threadIdx.x;
        float f[ADIM];
#pragma unroll
        for (int j = 0; j < FDIM; ++j) f[j] = fdg[(size_t)e * FDIM + j];
        f[FDIM] = rij[e];
        float acc = ca[0];
#pragma unroll
        for (int j = 0; j < ADIM; ++j) acc += f[j] * wa[j];
        unsigned rec[8];
#pragma unroll
        for (int j = 0; j < 5; ++j)
            rec[j] = (unsigned)f2bf(f[2 * j]) | ((unsigned)f2bf(f[2 * j + 1]) << 16);
        rec[5] = __float_as_uint(acc);
        rec[6] = 0; rec[7] = 0;
        uint4* dst = (uint4*)(emsg + (size_t)e * 16);
        dst[0] = make_uint4(rec[0], rec[1], rec[2], rec[3]);
        dst[1] = make_uint4(rec[4], rec[5], rec[6], rec[7]);
        sue[e] = (sul[e] > 0) ? su[e] : 0;
    }
}

// ---------------------------------------------------------------------------
// GAT iter 1 — FOUR nodes per wave. lane = (g = lane>>4 node-sub,
// pos = lane&15 neighbor slot). One load instruction covers 4 records
// (VMEM instr /4); group broadcasts via __shfl (ds_bpermute, computed lane).
// Epilogue applies W3/W2 once per node, weight regs shared across 4 nodes.
// Grid: 3125 blocks x 16 nodes.
// ---------------------------------------------------------------------------
__global__ __launch_bounds__(256) void k_gat1(
    const int* __restrict__ sse, const int* __restrict__ bsc,
    const float* __restrict__ t1A, const unsigned short* __restrict__ tfp,
    const unsigned short* __restrict__ emsg,
    const float* __restrict__ W2, const float* __restrict__ c2,
    const float* __restrict__ W3, const float* __restrict__ c3,
    const float* __restrict__ va, const float* __restrict__ vb,
    unsigned short* __restrict__ hp2bf, float* __restrict__ t1B,
    float* __restrict__ t2B)
{
    int wave = threadIdx.x >> 6;
    int lane = threadIdx.x & 63;
    int pos  = lane & 15;
    int gbase = lane & 48;                   // first lane of my 16-group
    int n0   = blockIdx.x * 16 + wave * 4;   // first of this wave's 4 nodes
    if (blockIdx.x == 0 && wave == 0) {
        hp2bf[lane] = 0;                     // zero pad row
        if (lane == 0) { t1B[0] = 0.f; t2B[0] = 0.f; }
    }

    // coalesced: element (n0*16 + lane) == node (n0 + lane/16), slot (lane&15)
    int kidx = sse[n0 * K_NB + lane];
    int ke   = bsc[n0 * K_NB + lane];
    float g2 = __uint_as_float(*(const unsigned*)(emsg + (size_t)(unsigned)ke * 16 + 10));
    float p  = t1A[kidx] + g2;
    p = (p > 0.f) ? p : 0.2f * p;            // leaky_relu(0.2)
    float lg = (kidx == 0) ? NEG_INF_F : p;  // pad mask

    // issue all 32 gathers: per k, each lane fetches short 'pos' of its
    // group's k-th record (4 records per instruction).
    unsigned wn_u[K_NB], wm_u[K_NB];
#pragma unroll
    for (int k = 0; k < K_NB; ++k) {
        int idxk = __shfl(kidx, gbase | k, 64);
        int ek   = __shfl(ke,   gbase | k, 64);
        const unsigned short* pk = tfp  + ((size_t)(unsigned)idxk * 16u + (unsigned)pos);
        const unsigned short* pe = emsg + ((size_t)(unsigned)ek   * 16u + (unsigned)pos);
        GLOADP_U16(wn_u[k], pk);
        GLOADP_U16(wm_u[k], pe);
    }

    // softmax within each 16-lane group (xor<16 stays in-group)
    float m = lg;
#pragma unroll
    for (int o = 8; o > 0; o >>= 1) m = fmaxf(m, __shfl_xor(m, o, 64));
    float ex = __expf(lg - m);
    float s = ex;
#pragma unroll
    for (int o = 8; o > 0; o >>= 1) s += __shfl_xor(s, o, 64);
    float alpha = ex / s;
    float beta = (kidx == 0) ? 0.f : alpha;  // masked alpha sum per group
#pragma unroll
    for (int o = 8; o > 0; o >>= 1) beta += __shfl_xor(beta, o, 64);

    DRAIN16(wn_u);
    HOLD16(wm_u);

    // alpha-weighted raw feature rows; lane (g,pos) owns feature 'pos' of node g
    float frn = 0.f, frm = 0.f;
#pragma unroll
    for (int k = 0; k < K_NB; ++k) {
        float ak = __shfl(alpha, gbase | k, 64);
        frn += ak * bf2f(wn_u[k]);           // tfp pads (pos>=9) are zero
        frm += ak * bf2f(wm_u[k]);           // pos>=10 garbage, never read
    }

    // weight columns once, reused for all 4 nodes
    float w3r[FDIM], w2r[ADIM];
#pragma unroll
    for (int j = 0; j < FDIM; ++j) w3r[j] = W3[j * H + lane];
#pragma unroll
    for (int j = 0; j < ADIM; ++j) w2r[j] = W2[j * H + lane];
    float c2r = c2[lane], c3r = c3[lane];
    float var = va[lane], vbr = vb[lane];

#pragma unroll
    for (int g = 0; g < 4; ++g) {
        float acc = c2r + readlane_f(beta, g * 16) * c3r;
#pragma unroll
        for (int j = 0; j < FDIM; ++j)
            acc += readlane_f(frn, g * 16 + j) * w3r[j];
#pragma unroll
        for (int j = 0; j < ADIM; ++j)
            acc += readlane_f(frm, g * 16 + j) * w2r[j];
        float o = (acc > 0.f) ? acc : expm1f(acc);   // elu
        hp2bf[(size_t)(n0 + g + 1) * H + lane] = f2bf(o);
        float ta = o * var, tb = o * vbr;            // f32-exact logit scalars
#pragma unroll
        for (int q = 32; q > 0; q >>= 1) {
            ta += __shfl_xor(ta, q, 64);
            tb += __shfl_xor(tb, q, 64);
        }
        if (lane == 0) { t1B[n0 + g + 1] = ta; t2B[n0 + g + 1] = tb; }
    }
}

// ---------------------------------------------------------------------------
// GAT iter 2, gather half (rows are full 64-wide — already 1 instr/record).
// Outputs gnm[row][lane] = pack(bf16(gn), bf16(gm)).
// ---------------------------------------------------------------------------
__global__ __launch_bounds__(256) void k_gat2(
    const int* __restrict__ sse, const int* __restrict__ bsc,
    const int* __restrict__ sue,
    const float* __restrict__ t1B, const float* __restrict__ t2B,
    const unsigned short* __restrict__ hp2bf,
    unsigned* __restrict__ gnm)
{
    int wave = threadIdx.x >> 6;
    int lane = threadIdx.x & 63;
    int n = blockIdx.x * 4 + wave;
    if (n == 0) gnm[lane] = 0;             // zero pad row
    if (n >= N_NODES) return;

    int kidx = 0, ksu = 0;
    float lg = NEG_INF_F;
    if (lane < K_NB) {
        kidx = sse[n * K_NB + lane];
        int ke = bsc[n * K_NB + lane];
        ksu = sue[ke];                     // row 0 = zero row for masked edges
        float p = t1B[kidx] + t2B[ksu];
        p = (p > 0.f) ? p : 0.2f * p;
        lg = (kidx == 0) ? NEG_INF_F : p;
    }

    unsigned wn_u[K_NB], wm_u[K_NB];
    int off = lane * 2;
#pragma unroll
    for (int k = 0; k < K_NB; ++k) {
        const unsigned short* pk = hp2bf + (size_t)readlane_i(kidx, k) * H;
        GLOAD_U16(wn_u[k], off, pk);
    }
#pragma unroll
    for (int k = 0; k < K_NB; ++k) {
        const unsigned short* ps = hp2bf + (size_t)readlane_i(ksu, k) * H;
        GLOAD_U16(wm_u[k], off, ps);
    }

    float m = lg;
#pragma unroll
    for (int o = 8; o > 0; o >>= 1) m = fmaxf(m, __shfl_xor(m, o, 64));
    float ex = __expf(lg - m);
    float s = ex;
#pragma unroll
    for (int o = 8; o > 0; o >>= 1) s += __shfl_xor(s, o, 64);
    float alpha = ex / s;

    DRAIN16(wn_u);
    HOLD16(wm_u);

    float gn = 0.f, gm = 0.f;              // alpha-weighted hp2 rows (64-dim)
#pragma unroll
    for (int k = 0; k < K_NB; ++k) {
        float ak = readlane_f(alpha, k);
        gn += ak * bf2f(wn_u[k]);
        gm += ak * bf2f(wm_u[k]);
    }
    gnm[(size_t)(n + 1) * H + lane] =
        (unsigned)f2bf(gn) | ((unsigned)f2bf(gm) << 16);
}

// ---------------------------------------------------------------------------
// GAT iter 2, projection half: hp3 = elu(gn@W_gat + gm@Wm_gat).
// Weights staged in LDS (32 KB/block) — removes the VGPR-residency gamble
// that defeated rounds 7/9/10. 2 rows/iter x 4 independent FMA chains.
// ---------------------------------------------------------------------------
__global__ __launch_bounds__(256) void k_proj(
    const unsigned* __restrict__ gnm,
    const float* __restrict__ W_gat, const float* __restrict__ Wm_gat,
    float* __restrict__ hp3)
{
    __shared__ float s_wg[H * H];
    __shared__ float s_wm[H * H];
    for (int q = threadIdx.x; q < H * H; q += 256) {
        s_wg[q] = W_gat[q];
        s_wm[q] = Wm_gat[q];
    }
    __syncthreads();
    int lane = threadIdx.x & 63;
    int wid = blockIdx.x * 4 + (threadIdx.x >> 6);
    int stride2 = gridDim.x * 4 * 2;
    for (int row = wid * 2; row <= N_NODES; row += stride2) {
        int row1 = row + 1;
        bool has1 = (row1 <= N_NODES);
        unsigned u0 = gnm[(size_t)row * H + lane];
        unsigned u1 = has1 ? gnm[(size_t)row1 * H + lane] : 0u;
        float an0 = 0.f, am0 = 0.f, an1 = 0.f, am1 = 0.f;
#pragma unroll
        for (int j = 0; j < H; ++j) {
            float wgj = s_wg[j * H + lane];
            float wmj = s_wm[j * H + lane];
            unsigned a = readlane_u(u0, j);
            unsigned b = readlane_u(u1, j);
            an0 += bf2f_lo(a) * wgj;
            am0 += bf2f_hi(a) * wmj;
            an1 += bf2f_lo(b) * wgj;
            am1 += bf2f_hi(b) * wmj;
        }
        float acc0 = an0 + am0;
        hp3[(size_t)row * H + lane] = (acc0 > 0.f) ? acc0 : expm1f(acc0);
        if (has1) {
            float acc1 = an1 + am1;
            hp3[(size_t)row1 * H + lane] = (acc1 > 0.f) ? acc1 : expm1f(acc1);
        }
    }
}

// ---------------------------------------------------------------------------
// out[b] = sum_m hp3[l_scope[b,m]] — 48 raw asm gathers all in flight.
// ---------------------------------------------------------------------------
__global__ __launch_bounds__(256) void k_out(
    const int* __restrict__ l_scope, const float* __restrict__ hp,
    float* __restrict__ out)
{
    int wave = threadIdx.x >> 6;
    int lane = threadIdx.x & 63;
    int b = blockIdx.x * 4 + wave;
    if (b >= B_MOL) return;
    int idx48 = (lane < MAXM_M) ? l_scope[b * MAXM_M + lane] : 0;
    float v[MAXM_M];
    int off = lane * 4;
#pragma unroll
    for (int m = 0; m < MAXM_M; ++m) {
        const float* pm = hp + (size_t)readlane_i(idx48, m) * H;
        GLOAD_F32(v[m], off, pm);
    }
    asm volatile("s_waitcnt vmcnt(0)"
        : "+v"(v[0]), "+v"(v[1]), "+v"(v[2]), "+v"(v[3]),
          "+v"(v[4]), "+v"(v[5]), "+v"(v[6]), "+v"(v[7]),
          "+v"(v[8]), "+v"(v[9]), "+v"(v[10]), "+v"(v[11]),
          "+v"(v[12]), "+v"(v[13]), "+v"(v[14]), "+v"(v[15]));
    asm volatile(""
        : "+v"(v[16]), "+v"(v[17]), "+v"(v[18]), "+v"(v[19]),
          "+v"(v[20]), "+v"(v[21]), "+v"(v[22]), "+v"(v[23]),
          "+v"(v[24]), "+v"(v[25]), "+v"(v[26]), "+v"(v[27]),
          "+v"(v[28]), "+v"(v[29]), "+v"(v[30]), "+v"(v[31]));
    asm volatile(""
        : "+v"(v[32]), "+v"(v[33]), "+v"(v[34]), "+v"(v[35]),
          "+v"(v[36]), "+v"(v[37]), "+v"(v[38]), "+v"(v[39]),
          "+v"(v[40]), "+v"(v[41]), "+v"(v[42]), "+v"(v[43]),
          "+v"(v[44]), "+v"(v[45]), "+v"(v[46]), "+v"(v[47]));
    float acc = 0.f;
#pragma unroll
    for (int m = 0; m < MAXM_M; ++m) acc += v[m];
    out[b * H + lane] = acc;
}

extern "C" void kernel_launch(void* const* d_in, const int* in_sizes, int n_in,
                              void* d_out, int out_size, void* d_ws, size_t ws_size,
                              hipStream_t stream)
{
    const float* tf     = (const float*)d_in[0];
    const float* fdg    = (const float*)d_in[1];
    const float* rij    = (const float*)d_in[2];
    const int*   sse    = (const int*)d_in[3];
    const int*   bsc    = (const int*)d_in[4];
    const int*   lsc    = (const int*)d_in[5];
    const int*   su     = (const int*)d_in[6];
    const int*   sul    = (const int*)d_in[7];
    const float* W_emb  = (const float*)d_in[8];
    const float* b_emb  = (const float*)d_in[9];
    const float* W_dist = (const float*)d_in[10];
    const float* b_dist = (const float*)d_in[11];
    const float* W_gat  = (const float*)d_in[12];
    const float* Wm_gat = (const float*)d_in[13];
    const float* a_gat  = (const float*)d_in[14];
    float* out = (float*)d_out;

    char* base = (char*)d_ws;
    size_t off = 0;
    auto alloc = [&](size_t bytes) {
        char* p = base + off;
        off = (off + bytes + 255) & ~(size_t)255;
        return p;
    };
    float* W2   = (float*)alloc(640 * 4);
    float* c2   = (float*)alloc(64 * 4);
    float* W3   = (float*)alloc(640 * 4);
    float* c3   = (float*)alloc(64 * 4);
    float* wa   = (float*)alloc(16 * 4);
    float* ca   = (float*)alloc(16 * 4);
    float* va   = (float*)alloc(64 * 4);
    float* vb   = (float*)alloc(64 * 4);
    float* wv9  = (float*)alloc(16 * 4);
    float* cv   = (float*)alloc(16 * 4);
    float* t1A  = (float*)alloc((size_t)(N_NODES + 1) * 4);
    float* t1B  = (float*)alloc((size_t)(N_NODES + 1) * 4);
    float* t2B  = (float*)alloc((size_t)(N_NODES + 1) * 4);
    int*   sue  = (int*)alloc((size_t)E_EDGES * 4);
    unsigned short* tfp   = (unsigned short*)alloc((size_t)(N_NODES + 1) * 16 * 2);
    unsigned short* hp2bf = (unsigned short*)alloc((size_t)(N_NODES + 1) * H * 2);
    unsigned* gnm = (unsigned*)alloc((size_t)(N_NODES + 1) * H * 4);
    // emsg (25.6MB) and hp3 (12.8MB) alias: emsg dead before k_proj writes hp3
    char* big = alloc((size_t)E_EDGES * 32);
    unsigned short* emsg = (unsigned short*)big;
    float* hp3 = (float*)big;

    k_fold<<<dim3(1), dim3(256), 0, stream>>>(
        W_emb, b_emb, W_dist, b_dist, W_gat, Wm_gat, a_gat,
        W2, c2, W3, c3, wa, ca, va, vb, wv9, cv);

    k_pre<<<dim3(PRE_NODE_BLOCKS + EDGE_BLOCKS), dim3(256), 0, stream>>>(
        tf, fdg, rij, su, sul, wa, ca, wv9, cv, t1A, tfp, emsg, sue);

    k_gat1<<<dim3(N_NODES / 16), dim3(256), 0, stream>>>(
        sse, bsc, t1A, tfp, emsg, W2, c2, W3, c3, va, vb, hp2bf, t1B, t2B);

    k_gat2<<<dim3((N_NODES + 3) / 4), dim3(256), 0, stream>>>(
        sse, bsc, sue, t1B, t2B, hp2bf, gnm);

    k_proj<<<dim3(1024), dim3(256), 0, stream>>>(gnm, W_gat, Wm_gat, hp3);

    k_out<<<dim3(B_MOL / 4), dim3(256), 0, stream>>>(lsc, hp3, out);
}

// Round 13
// 212.572 us; speedup vs baseline: 1.1737x; 1.1737x over previous
//
#include <hip/hip_runtime.h>
#include <hip/hip_bf16.h>

#define N_NODES 50000
#define K_NB 16
#define E_EDGES 800000
#define B_MOL 1024
#define MAXM_M 48
#define FDIM 9
#define ADIM 10
#define H 64
#define NEG_INF_F (-1e9f)
#define PRE_NODE_BLOCKS 196  /* 1 thread per node */
#define EDGE_BLOCKS 3125     /* 256 edges per block */

typedef __bf16 bf16x8 __attribute__((ext_vector_type(8)));
typedef float f32x4 __attribute__((ext_vector_type(4)));

__device__ inline float readlane_f(float v, int l) {
    return __int_as_float(__builtin_amdgcn_readlane(__float_as_int(v), l));
}
__device__ inline int readlane_i(int v, int l) {
    return __builtin_amdgcn_readlane(v, l);
}
__device__ inline float bf2f(unsigned u) {         // u = zero-extended bf16
    return __uint_as_float(u << 16);
}
__device__ inline unsigned short f2bf(float f) {   // round-to-nearest-even
    unsigned x = __float_as_uint(f);
    return (unsigned short)((x + 0x7fffu + ((x >> 16) & 1u)) >> 16);
}

// Raw gather, wave-uniform SGPR base + per-lane VGPR byte offset.
#define GLOAD_U16(dst, voff, sbase) \
    asm volatile("global_load_ushort %0, %1, %2" : "=v"(dst) : "v"(voff), "s"(sbase))
#define GLOAD_F32(dst, voff, sbase) \
    asm volatile("global_load_dword %0, %1, %2" : "=v"(dst) : "v"(voff), "s"(sbase))

#define DRAIN16(a) \
    asm volatile("s_waitcnt vmcnt(0)" \
        : "+v"(a[0]), "+v"(a[1]), "+v"(a[2]), "+v"(a[3]), \
          "+v"(a[4]), "+v"(a[5]), "+v"(a[6]), "+v"(a[7]), \
          "+v"(a[8]), "+v"(a[9]), "+v"(a[10]), "+v"(a[11]), \
          "+v"(a[12]), "+v"(a[13]), "+v"(a[14]), "+v"(a[15]))
#define HOLD16(a) \
    asm volatile("" \
        : "+v"(a[0]), "+v"(a[1]), "+v"(a[2]), "+v"(a[3]), \
          "+v"(a[4]), "+v"(a[5]), "+v"(a[6]), "+v"(a[7]), \
          "+v"(a[8]), "+v"(a[9]), "+v"(a[10]), "+v"(a[11]), \
          "+v"(a[12]), "+v"(a[13]), "+v"(a[14]), "+v"(a[15]))

// ---------------------------------------------------------------------------
// Fold all weight algebra (single block):
//   va/vb, W2/c2, W3/c3, wa/ca, wv9/cv (as before), plus
//   WintT[64][128] bf16: WintT[n][2j]=W_gat[j][n], WintT[n][2j+1]=Wm_gat[j][n]
//   (transposed interleaved weights for the MFMA projection's B fragments).
// ---------------------------------------------------------------------------
__global__ __launch_bounds__(256) void k_fold(
    const float* __restrict__ W_emb, const float* __restrict__ b_emb,
    const float* __restrict__ W_dist, const float* __restrict__ b_dist,
    const float* __restrict__ W_gat, const float* __restrict__ Wm_gat,
    const float* __restrict__ a_gat,
    float* __restrict__ W2, float* __restrict__ c2,
    float* __restrict__ W3, float* __restrict__ c3,
    float* __restrict__ wa, float* __restrict__ ca,
    float* __restrict__ va, float* __restrict__ vb,
    float* __restrict__ wv9, float* __restrict__ cv,
    unsigned short* __restrict__ WintT)
{
    __shared__ float s_va[64], s_vb[64];
    int tid = threadIdx.x;
    int h = tid & 63, g = tid >> 6;
    if (g == 0) {            // va[h] = W_gat[h,:] . a1
        float acc = 0.f;
        for (int t = 0; t < H; ++t) acc += W_gat[h * H + t] * a_gat[t];
        s_va[h] = acc; va[h] = acc;
    } else if (g == 1) {     // vb[h] = Wm_gat[h,:] . a2
        float acc = 0.f;
        for (int t = 0; t < H; ++t) acc += Wm_gat[h * H + t] * a_gat[H + t];
        s_vb[h] = acc; vb[h] = acc;
    } else if (g == 2) {     // c2
        float acc = 0.f;
        for (int t = 0; t < H; ++t) acc += b_dist[t] * Wm_gat[t * H + h];
        c2[h] = acc;
    } else {                 // c3
        float acc = 0.f;
        for (int t = 0; t < H; ++t) acc += b_emb[t] * W_gat[t * H + h];
        c3[h] = acc;
    }
    __syncthreads();
    for (int q = tid; q < 640; q += 256) {   // W2[j,h]
        int j = q >> 6, hh = q & 63;
        float acc = 0.f;
        for (int t = 0; t < H; ++t) acc += W_dist[j * H + t] * Wm_gat[t * H + hh];
        W2[q] = acc;
    }
    for (int q = tid; q < 576; q += 256) {   // W3[j,h]
        int j = q >> 6, hh = q & 63;
        float acc = 0.f;
        for (int t = 0; t < H; ++t) acc += W_emb[j * H + t] * W_gat[t * H + hh];
        W3[q] = acc;
    }
    for (int q = tid; q < H * 2 * H; q += 256) {  // WintT[n][k], 8192 entries
        int n = q >> 7, k = q & 127;
        float v = (k & 1) ? Wm_gat[(k >> 1) * H + n] : W_gat[(k >> 1) * H + n];
        WintT[q] = f2bf(v);
    }
    if (tid < ADIM) {                         // wa
        float acc = 0.f;
        for (int t = 0; t < H; ++t) acc += W_dist[tid * H + t] * s_vb[t];
        wa[tid] = acc;
    } else if (tid == ADIM) {                 // ca
        float acc = 0.f;
        for (int t = 0; t < H; ++t) acc += b_dist[t] * s_vb[t];
        ca[0] = acc;
    } else if (tid >= 16 && tid < 16 + FDIM) {// wv9
        int j = tid - 16;
        float acc = 0.f;
        for (int t = 0; t < H; ++t) acc += W_emb[j * H + t] * s_va[t];
        wv9[j] = acc;
    } else if (tid == 31) {                   // cv
        float acc = 0.f;
        for (int t = 0; t < H; ++t) acc += b_emb[t] * s_va[t];
        cv[0] = acc;
    }
}

// ---------------------------------------------------------------------------
// Pre-pass: t1A + tfp records (node side); emsg records + sue (edge side).
// ---------------------------------------------------------------------------
__global__ __launch_bounds__(256) void k_pre(
    const float* __restrict__ tf, const float* __restrict__ fdg,
    const float* __restrict__ rij,
    const int* __restrict__ su, const int* __restrict__ sul,
    const float* __restrict__ wa, const float* __restrict__ ca,
    const float* __restrict__ wv9, const float* __restrict__ cv,
    float* __restrict__ t1A, unsigned short* __restrict__ tfp,
    unsigned short* __restrict__ emsg, int* __restrict__ sue)
{
    int bid = blockIdx.x;
    if (bid < PRE_NODE_BLOCKS) {
        int n = bid * 256 + threadIdx.x;
        if (n == 0) {                        // zero pad row
            t1A[0] = 0.f;
            uint4 z = make_uint4(0, 0, 0, 0);
            ((uint4*)tfp)[0] = z; ((uint4*)tfp)[1] = z;
        }
        if (n >= N_NODES) return;
        float f[FDIM];
        float acc = cv[0];
#pragma unroll
        for (int j = 0; j < FDIM; ++j) {
            f[j] = tf[n * FDIM + j];
            acc += f[j] * wv9[j];
        }
        t1A[n + 1] = acc;
        unsigned rec[8];
#pragma unroll
        for (int j = 0; j < 4; ++j)
            rec[j] = (unsigned)f2bf(f[2 * j]) | ((unsigned)f2bf(f[2 * j + 1]) << 16);
        rec[4] = (unsigned)f2bf(f[8]);
        rec[5] = 0; rec[6] = 0; rec[7] = 0;
        uint4* dst = (uint4*)(tfp + (size_t)(n + 1) * 16);
        dst[0] = make_uint4(rec[0], rec[1], rec[2], rec[3]);
        dst[1] = make_uint4(rec[4], rec[5], rec[6], rec[7]);
    } else {
        int e = (bid - PRE_NODE_BLOCKS) * 256 + threadIdx.x;
        float f[ADIM];
#pragma unroll
        for (int j = 0; j < FDIM; ++j) f[j] = fdg[(size_t)e * FDIM + j];
        f[FDIM] = rij[e];
        float acc = ca[0];
#pragma unroll
        for (int j = 0; j < ADIM; ++j) acc += f[j] * wa[j];
        unsigned rec[8];
#pragma unroll
        for (int j = 0; j < 5; ++j)
            rec[j] = (unsigned)f2bf(f[2 * j]) | ((unsigned)f2bf(f[2 * j + 1]) << 16);
        rec[5] = __float_as_uint(acc);
        rec[6] = 0; rec[7] = 0;
        uint4* dst = (uint4*)(emsg + (size_t)e * 16);
        dst[0] = make_uint4(rec[0], rec[1], rec[2], rec[3]);
        dst[1] = make_uint4(rec[4], rec[5], rec[6], rec[7]);
        sue[e] = (sul[e] > 0) ? su[e] : 0;
    }
}

// ---------------------------------------------------------------------------
// GAT iter 1 (round-10 version — measured 42us; round-11 4-node variant
// regressed ~13us and was reverted). One wave per node, lane = feature.
// ---------------------------------------------------------------------------
__global__ __launch_bounds__(256) void k_gat1(
    const int* __restrict__ sse, const int* __restrict__ bsc,
    const float* __restrict__ t1A, const unsigned short* __restrict__ tfp,
    const unsigned short* __restrict__ emsg,
    const float* __restrict__ W2, const float* __restrict__ c2,
    const float* __restrict__ W3, const float* __restrict__ c3,
    const float* __restrict__ va, const float* __restrict__ vb,
    unsigned short* __restrict__ hp2bf, float* __restrict__ t1B,
    float* __restrict__ t2B)
{
    int wave = threadIdx.x >> 6;
    int lane = threadIdx.x & 63;
    int n = blockIdx.x * 4 + wave;
    if (n == 0) {
        hp2bf[lane] = 0;
        if (lane == 0) { t1B[0] = 0.f; t2B[0] = 0.f; }
    }
    if (n >= N_NODES) return;

    int kidx = 0, ke = 0;
    float lg = NEG_INF_F;
    if (lane < K_NB) {
        kidx = sse[n * K_NB + lane];
        ke   = bsc[n * K_NB + lane];
        float g2 = __uint_as_float(*(const unsigned*)(emsg + (size_t)ke * 16 + 10));
        float p = t1A[kidx] + g2;
        p = (p > 0.f) ? p : 0.2f * p;      // leaky_relu(0.2)
        lg = (kidx == 0) ? NEG_INF_F : p;  // pad mask
    }

    unsigned wn_u[K_NB], wm_u[K_NB];
    int offr = (lane & 15) * 2;            // short index within 32B record
#pragma unroll
    for (int k = 0; k < K_NB; ++k) {
        const unsigned short* pk = tfp + (size_t)readlane_i(kidx, k) * 16;
        GLOAD_U16(wn_u[k], offr, pk);
    }
#pragma unroll
    for (int k = 0; k < K_NB; ++k) {
        const unsigned short* pe = emsg + (size_t)readlane_i(ke, k) * 16;
        GLOAD_U16(wm_u[k], offr, pe);
    }

    // softmax across the 16-lane group — overlaps the gathers
    float m = lg;
#pragma unroll
    for (int o = 8; o > 0; o >>= 1) m = fmaxf(m, __shfl_xor(m, o, 64));
    float ex = __expf(lg - m);
    float s = ex;
#pragma unroll
    for (int o = 8; o > 0; o >>= 1) s += __shfl_xor(s, o, 64);
    float alpha = ex / s;

    DRAIN16(wn_u);
    HOLD16(wm_u);

    float fr = 0.f, frm = 0.f, beta = 0.f;
#pragma unroll
    for (int k = 0; k < K_NB; ++k) {
        float ak = readlane_f(alpha, k);
        fr  += ak * bf2f(wn_u[k]);         // lanes 9..15 read record pad zeros
        frm += ak * bf2f(wm_u[k]);         // lanes >= ADIM garbage, never read
        beta += (readlane_i(kidx, k) > 0) ? ak : 0.f;
    }
    float acc = c2[lane] + beta * c3[lane];
#pragma unroll
    for (int j = 0; j < FDIM; ++j) acc += readlane_f(fr, j) * W3[j * H + lane];
#pragma unroll
    for (int j = 0; j < ADIM; ++j) acc += readlane_f(frm, j) * W2[j * H + lane];
    float o = (acc > 0.f) ? acc : expm1f(acc);   // elu
    hp2bf[(size_t)(n + 1) * H + lane] = f2bf(o);
    float ta = o * va[lane], tb = o * vb[lane];  // f32-exact logit scalars
#pragma unroll
    for (int q = 32; q > 0; q >>= 1) {
        ta += __shfl_xor(ta, q, 64);
        tb += __shfl_xor(tb, q, 64);
    }
    if (lane == 0) { t1B[n + 1] = ta; t2B[n + 1] = tb; }
}

// ---------------------------------------------------------------------------
// GAT iter 2, gather half. All 32 row gathers hit ONE 6.4MB bf16 table.
// Outputs gnm[row][lane] = pack(bf16(gn), bf16(gm)).
// ---------------------------------------------------------------------------
__global__ __launch_bounds__(256) void k_gat2(
    const int* __restrict__ sse, const int* __restrict__ bsc,
    const int* __restrict__ sue,
    const float* __restrict__ t1B, const float* __restrict__ t2B,
    const unsigned short* __restrict__ hp2bf,
    unsigned* __restrict__ gnm)
{
    int wave = threadIdx.x >> 6;
    int lane = threadIdx.x & 63;
    int n = blockIdx.x * 4 + wave;
    if (n == 0) gnm[lane] = 0;             // zero pad row
    if (n >= N_NODES) return;

    int kidx = 0, ksu = 0;
    float lg = NEG_INF_F;
    if (lane < K_NB) {
        kidx = sse[n * K_NB + lane];
        int ke = bsc[n * K_NB + lane];
        ksu = sue[ke];                     // row 0 = zero row for masked edges
        float p = t1B[kidx] + t2B[ksu];
        p = (p > 0.f) ? p : 0.2f * p;
        lg = (kidx == 0) ? NEG_INF_F : p;
    }

    unsigned wn_u[K_NB], wm_u[K_NB];
    int off = lane * 2;
#pragma unroll
    for (int k = 0; k < K_NB; ++k) {
        const unsigned short* pk = hp2bf + (size_t)readlane_i(kidx, k) * H;
        GLOAD_U16(wn_u[k], off, pk);
    }
#pragma unroll
    for (int k = 0; k < K_NB; ++k) {
        const unsigned short* ps = hp2bf + (size_t)readlane_i(ksu, k) * H;
        GLOAD_U16(wm_u[k], off, ps);
    }

    float m = lg;
#pragma unroll
    for (int o = 8; o > 0; o >>= 1) m = fmaxf(m, __shfl_xor(m, o, 64));
    float ex = __expf(lg - m);
    float s = ex;
#pragma unroll
    for (int o = 8; o > 0; o >>= 1) s += __shfl_xor(s, o, 64);
    float alpha = ex / s;

    DRAIN16(wn_u);
    HOLD16(wm_u);

    float gn = 0.f, gm = 0.f;              // alpha-weighted hp2 rows (64-dim)
#pragma unroll
    for (int k = 0; k < K_NB; ++k) {
        float ak = readlane_f(alpha, k);
        gn += ak * bf2f(wn_u[k]);
        gm += ak * bf2f(wm_u[k]);
    }
    gnm[(size_t)(n + 1) * H + lane] =
        (unsigned)f2bf(gn) | ((unsigned)f2bf(gm) << 16);
}

// ---------------------------------------------------------------------------
// GAT iter 2, projection half — MFMA GEMM:
//   hp3[50001,64] = elu( gnmx[50001,128] @ Wint[128,64] )
// gnm's packed (gn,gm) uints ARE the K=128 bf16 A-rows (k=2j:gn, 2j+1:gm);
// WintT[n][k] supplies contiguous B fragments. Per 16-row block: 4 uint4
// A-loads + 16 v_mfma_f32_16x16x32_bf16. B (64 VGPRs) loaded once per wave.
// A-frag: A[m=lane&15][k=(lane>>4)*8+j]; C/D: col=lane&15, row=(lane>>4)*4+r.
// ---------------------------------------------------------------------------
__global__ __launch_bounds__(256, 1) void k_proj(
    const unsigned* __restrict__ gnm,
    const unsigned short* __restrict__ WintT,
    float* __restrict__ hp3)
{
    int lane = threadIdx.x & 63;
    int m = lane & 15, q = lane >> 4;
    int waveid = (blockIdx.x * 256 + threadIdx.x) >> 6;   // 0..1023

    union UB { uint4 u; bf16x8 v; };
    bf16x8 bfr[4][4];                       // [kk][t]
#pragma unroll
    for (int t = 0; t < 4; ++t) {
        const unsigned short* bp = WintT + (size_t)(t * 16 + m) * 128 + q * 8;
#pragma unroll
        for (int kk = 0; kk < 4; ++kk) {
            UB ub; ub.u = *(const uint4*)(bp + kk * 32);
            bfr[kk][t] = ub.v;
        }
    }

    const int NBLK = (N_NODES + 16) / 16;   // 3126 x 16 rows covers 50001
    for (int blk = waveid; blk < NBLK; blk += 1024) {
        int row0 = blk * 16;
        int rowm = row0 + m;
        if (rowm > N_NODES) rowm = N_NODES; // clamped load, store is guarded
        const unsigned* ap = gnm + (size_t)rowm * H + q * 4;
        f32x4 acc[4];
        UB ua[4];
#pragma unroll
        for (int kk = 0; kk < 4; ++kk) ua[kk].u = *(const uint4*)(ap + kk * 16);
#pragma unroll
        for (int t = 0; t < 4; ++t) {
            acc[t] = (f32x4){0.f, 0.f, 0.f, 0.f};
#pragma unroll
            for (int kk = 0; kk < 4; ++kk)
                acc[t] = __builtin_amdgcn_mfma_f32_16x16x32_bf16(
                    ua[kk].v, bfr[kk][t], acc[t], 0, 0, 0);
        }
#pragma unroll
        for (int t = 0; t < 4; ++t) {
#pragma unroll
            for (int r = 0; r < 4; ++r) {
                int row = row0 + q * 4 + r;
                if (row <= N_NODES) {
                    float v = acc[t][r];
                    hp3[(size_t)row * H + t * 16 + m] =
                        (v > 0.f) ? v : expm1f(v);
                }
            }
        }
    }
}

// ---------------------------------------------------------------------------
// out[b] = sum_m hp3[l_scope[b,m]] — 48 raw asm gathers all in flight.
// ---------------------------------------------------------------------------
__global__ __launch_bounds__(256) void k_out(
    const int* __restrict__ l_scope, const float* __restrict__ hp,
    float* __restrict__ out)
{
    int wave = threadIdx.x >> 6;
    int lane = threadIdx.x & 63;
    int b = blockIdx.x * 4 + wave;
    if (b >= B_MOL) return;
    int idx48 = (lane < MAXM_M) ? l_scope[b * MAXM_M + lane] : 0;
    float v[MAXM_M];
    int off = lane * 4;
#pragma unroll
    for (int m = 0; m < MAXM_M; ++m) {
        const float* pm = hp + (size_t)readlane_i(idx48, m) * H;
        GLOAD_F32(v[m], off, pm);
    }
    asm volatile("s_waitcnt vmcnt(0)"
        : "+v"(v[0]), "+v"(v[1]), "+v"(v[2]), "+v"(v[3]),
          "+v"(v[4]), "+v"(v[5]), "+v"(v[6]), "+v"(v[7]),
          "+v"(v[8]), "+v"(v[9]), "+v"(v[10]), "+v"(v[11]),
          "+v"(v[12]), "+v"(v[13]), "+v"(v[14]), "+v"(v[15]));
    asm volatile(""
        : "+v"(v[16]), "+v"(v[17]), "+v"(v[18]), "+v"(v[19]),
          "+v"(v[20]), "+v"(v[21]), "+v"(v[22]), "+v"(v[23]),
          "+v"(v[24]), "+v"(v[25]), "+v"(v[26]), "+v"(v[27]),
          "+v"(v[28]), "+v"(v[29]), "+v"(v[30]), "+v"(v[31]));
    asm volatile(""
        : "+v"(v[32]), "+v"(v[33]), "+v"(v[34]), "+v"(v[35]),
          "+v"(v[36]), "+v"(v[37]), "+v"(v[38]), "+v"(v[39]),
          "+v"(v[40]), "+v"(v[41]), "+v"(v[42]), "+v"(v[43]),
          "+v"(v[44]), "+v"(v[45]), "+v"(v[46]), "+v"(v[47]));
    float acc = 0.f;
#pragma unroll
    for (int m = 0; m < MAXM_M; ++m) acc += v[m];
    out[b * H + lane] = acc;
}

extern "C" void kernel_launch(void* const* d_in, const int* in_sizes, int n_in,
                              void* d_out, int out_size, void* d_ws, size_t ws_size,
                              hipStream_t stream)
{
    const float* tf     = (const float*)d_in[0];
    const float* fdg    = (const float*)d_in[1];
    const float* rij    = (const float*)d_in[2];
    const int*   sse    = (const int*)d_in[3];
    const int*   bsc    = (const int*)d_in[4];
    const int*   lsc    = (const int*)d_in[5];
    const int*   su     = (const int*)d_in[6];
    const int*   sul    = (const int*)d_in[7];
    const float* W_emb  = (const float*)d_in[8];
    const float* b_emb  = (const float*)d_in[9];
    const float* W_dist = (const float*)d_in[10];
    const float* b_dist = (const float*)d_in[11];
    const float* W_gat  = (const float*)d_in[12];
    const float* Wm_gat = (const float*)d_in[13];
    const float* a_gat  = (const float*)d_in[14];
    float* out = (float*)d_out;

    char* base = (char*)d_ws;
    size_t off = 0;
    auto alloc = [&](size_t bytes) {
        char* p = base + off;
        off = (off + bytes + 255) & ~(size_t)255;
        return p;
    };
    float* W2   = (float*)alloc(640 * 4);
    float* c2   = (float*)alloc(64 * 4);
    float* W3   = (float*)alloc(640 * 4);
    float* c3   = (float*)alloc(64 * 4);
    float* wa   = (float*)alloc(16 * 4);
    float* ca   = (float*)alloc(16 * 4);
    float* va   = (float*)alloc(64 * 4);
    float* vb   = (float*)alloc(64 * 4);
    float* wv9  = (float*)alloc(16 * 4);
    float* cv   = (float*)alloc(16 * 4);
    unsigned short* WintT = (unsigned short*)alloc(64 * 128 * 2);
    float* t1A  = (float*)alloc((size_t)(N_NODES + 1) * 4);
    float* t1B  = (float*)alloc((size_t)(N_NODES + 1) * 4);
    float* t2B  = (float*)alloc((size_t)(N_NODES + 1) * 4);
    int*   sue  = (int*)alloc((size_t)E_EDGES * 4);
    unsigned short* tfp   = (unsigned short*)alloc((size_t)(N_NODES + 1) * 16 * 2);
    unsigned short* hp2bf = (unsigned short*)alloc((size_t)(N_NODES + 1) * H * 2);
    unsigned* gnm = (unsigned*)alloc((size_t)(N_NODES + 1) * H * 4);
    // emsg (25.6MB) and hp3 (12.8MB) alias: emsg dead before k_proj writes hp3
    char* big = alloc((size_t)E_EDGES * 32);
    unsigned short* emsg = (unsigned short*)big;
    float* hp3 = (float*)big;

    k_fold<<<dim3(1), dim3(256), 0, stream>>>(
        W_emb, b_emb, W_dist, b_dist, W_gat, Wm_gat, a_gat,
        W2, c2, W3, c3, wa, ca, va, vb, wv9, cv, WintT);

    k_pre<<<dim3(PRE_NODE_BLOCKS + EDGE_BLOCKS), dim3(256), 0, stream>>>(
        tf, fdg, rij, su, sul, wa, ca, wv9, cv, t1A, tfp, emsg, sue);

    dim3 gat_grid((N_NODES + 3) / 4);
    k_gat1<<<gat_grid, dim3(256), 0, stream>>>(
        sse, bsc, t1A, tfp, emsg, W2, c2, W3, c3, va, vb, hp2bf, t1B, t2B);

    k_gat2<<<gat_grid, dim3(256), 0, stream>>>(
        sse, bsc, sue, t1B, t2B, hp2bf, gnm);

    k_proj<<<dim3(256), dim3(256), 0, stream>>>(gnm, WintT, hp3);

    k_out<<<dim3(B_MOL / 4), dim3(256), 0, stream>>>(lsc, hp3, out);
}

// Round 14
// 208.354 us; speedup vs baseline: 1.1974x; 1.0202x over previous
//
#include <hip/hip_runtime.h>
#include <hip/hip_bf16.h>

#define N_NODES 50000
#define K_NB 16
#define E_EDGES 800000
#define B_MOL 1024
#define MAXM_M 48
#define FDIM 9
#define ADIM 10
#define H 64
#define NEG_INF_F (-1e9f)
#define PRE_NODE_BLOCKS 196  /* 1 thread per node */
#define EDGE_BLOCKS 3125     /* 256 edges per block */

typedef __bf16 bf16x8 __attribute__((ext_vector_type(8)));
typedef float f32x4 __attribute__((ext_vector_type(4)));

__device__ inline float readlane_f(float v, int l) {
    return __int_as_float(__builtin_amdgcn_readlane(__float_as_int(v), l));
}
__device__ inline int readlane_i(int v, int l) {
    return __builtin_amdgcn_readlane(v, l);
}
__device__ inline float bf2f(unsigned u) {         // u = zero-extended bf16
    return __uint_as_float(u << 16);
}
__device__ inline unsigned short f2bf(float f) {   // round-to-nearest-even
    unsigned x = __float_as_uint(f);
    return (unsigned short)((x + 0x7fffu + ((x >> 16) & 1u)) >> 16);
}

// Raw gather, wave-uniform SGPR base + per-lane VGPR byte offset.
#define GLOAD_U16(dst, voff, sbase) \
    asm volatile("global_load_ushort %0, %1, %2" : "=v"(dst) : "v"(voff), "s"(sbase))
#define GLOAD_F32(dst, voff, sbase) \
    asm volatile("global_load_dword %0, %1, %2" : "=v"(dst) : "v"(voff), "s"(sbase))

#define DRAIN16(a) \
    asm volatile("s_waitcnt vmcnt(0)" \
        : "+v"(a[0]), "+v"(a[1]), "+v"(a[2]), "+v"(a[3]), \
          "+v"(a[4]), "+v"(a[5]), "+v"(a[6]), "+v"(a[7]), \
          "+v"(a[8]), "+v"(a[9]), "+v"(a[10]), "+v"(a[11]), \
          "+v"(a[12]), "+v"(a[13]), "+v"(a[14]), "+v"(a[15]))
#define HOLD16(a) \
    asm volatile("" \
        : "+v"(a[0]), "+v"(a[1]), "+v"(a[2]), "+v"(a[3]), \
          "+v"(a[4]), "+v"(a[5]), "+v"(a[6]), "+v"(a[7]), \
          "+v"(a[8]), "+v"(a[9]), "+v"(a[10]), "+v"(a[11]), \
          "+v"(a[12]), "+v"(a[13]), "+v"(a[14]), "+v"(a[15]))

// ---------------------------------------------------------------------------
// Fold all weight algebra (single block):
//   va/vb, W2/c2, W3/c3, wa/ca, wv9/cv, plus
//   WintT[64][128] bf16: WintT[n][2j]=W_gat[j][n], WintT[n][2j+1]=Wm_gat[j][n]
// ---------------------------------------------------------------------------
__global__ __launch_bounds__(256) void k_fold(
    const float* __restrict__ W_emb, const float* __restrict__ b_emb,
    const float* __restrict__ W_dist, const float* __restrict__ b_dist,
    const float* __restrict__ W_gat, const float* __restrict__ Wm_gat,
    const float* __restrict__ a_gat,
    float* __restrict__ W2, float* __restrict__ c2,
    float* __restrict__ W3, float* __restrict__ c3,
    float* __restrict__ wa, float* __restrict__ ca,
    float* __restrict__ va, float* __restrict__ vb,
    float* __restrict__ wv9, float* __restrict__ cv,
    unsigned short* __restrict__ WintT)
{
    __shared__ float s_va[64], s_vb[64];
    int tid = threadIdx.x;
    int h = tid & 63, g = tid >> 6;
    if (g == 0) {            // va[h] = W_gat[h,:] . a1
        float acc = 0.f;
        for (int t = 0; t < H; ++t) acc += W_gat[h * H + t] * a_gat[t];
        s_va[h] = acc; va[h] = acc;
    } else if (g == 1) {     // vb[h] = Wm_gat[h,:] . a2
        float acc = 0.f;
        for (int t = 0; t < H; ++t) acc += Wm_gat[h * H + t] * a_gat[H + t];
        s_vb[h] = acc; vb[h] = acc;
    } else if (g == 2) {     // c2
        float acc = 0.f;
        for (int t = 0; t < H; ++t) acc += b_dist[t] * Wm_gat[t * H + h];
        c2[h] = acc;
    } else {                 // c3
        float acc = 0.f;
        for (int t = 0; t < H; ++t) acc += b_emb[t] * W_gat[t * H + h];
        c3[h] = acc;
    }
    __syncthreads();
    for (int q = tid; q < 640; q += 256) {   // W2[j,h]
        int j = q >> 6, hh = q & 63;
        float acc = 0.f;
        for (int t = 0; t < H; ++t) acc += W_dist[j * H + t] * Wm_gat[t * H + hh];
        W2[q] = acc;
    }
    for (int q = tid; q < 576; q += 256) {   // W3[j,h]
        int j = q >> 6, hh = q & 63;
        float acc = 0.f;
        for (int t = 0; t < H; ++t) acc += W_emb[j * H + t] * W_gat[t * H + hh];
        W3[q] = acc;
    }
    for (int q = tid; q < H * 2 * H; q += 256) {  // WintT[n][k], 8192 entries
        int n = q >> 7, k = q & 127;
        float v = (k & 1) ? Wm_gat[(k >> 1) * H + n] : W_gat[(k >> 1) * H + n];
        WintT[q] = f2bf(v);
    }
    if (tid < ADIM) {                         // wa
        float acc = 0.f;
        for (int t = 0; t < H; ++t) acc += W_dist[tid * H + t] * s_vb[t];
        wa[tid] = acc;
    } else if (tid == ADIM) {                 // ca
        float acc = 0.f;
        for (int t = 0; t < H; ++t) acc += b_dist[t] * s_vb[t];
        ca[0] = acc;
    } else if (tid >= 16 && tid < 16 + FDIM) {// wv9
        int j = tid - 16;
        float acc = 0.f;
        for (int t = 0; t < H; ++t) acc += W_emb[j * H + t] * s_va[t];
        wv9[j] = acc;
    } else if (tid == 31) {                   // cv
        float acc = 0.f;
        for (int t = 0; t < H; ++t) acc += b_emb[t] * s_va[t];
        cv[0] = acc;
    }
}

// ---------------------------------------------------------------------------
// Pre-pass: t1A + tfp records (node side); emsg records + sue (edge side).
// ---------------------------------------------------------------------------
__global__ __launch_bounds__(256) void k_pre(
    const float* __restrict__ tf, const float* __restrict__ fdg,
    const float* __restrict__ rij,
    const int* __restrict__ su, const int* __restrict__ sul,
    const float* __restrict__ wa, const float* __restrict__ ca,
    const float* __restrict__ wv9, const float* __restrict__ cv,
    float* __restrict__ t1A, unsigned short* __restrict__ tfp,
    unsigned short* __restrict__ emsg, int* __restrict__ sue)
{
    int bid = blockIdx.x;
    if (bid < PRE_NODE_BLOCKS) {
        int n = bid * 256 + threadIdx.x;
        if (n == 0) {                        // zero pad row
            t1A[0] = 0.f;
            uint4 z = make_uint4(0, 0, 0, 0);
            ((uint4*)tfp)[0] = z; ((uint4*)tfp)[1] = z;
        }
        if (n >= N_NODES) return;
        float f[FDIM];
        float acc = cv[0];
#pragma unroll
        for (int j = 0; j < FDIM; ++j) {
            f[j] = tf[n * FDIM + j];
            acc += f[j] * wv9[j];
        }
        t1A[n + 1] = acc;
        unsigned rec[8];
#pragma unroll
        for (int j = 0; j < 4; ++j)
            rec[j] = (unsigned)f2bf(f[2 * j]) | ((unsigned)f2bf(f[2 * j + 1]) << 16);
        rec[4] = (unsigned)f2bf(f[8]);
        rec[5] = 0; rec[6] = 0; rec[7] = 0;
        uint4* dst = (uint4*)(tfp + (size_t)(n + 1) * 16);
        dst[0] = make_uint4(rec[0], rec[1], rec[2], rec[3]);
        dst[1] = make_uint4(rec[4], rec[5], rec[6], rec[7]);
    } else {
        int e = (bid - PRE_NODE_BLOCKS) * 256 + threadIdx.x;
        float f[ADIM];
#pragma unroll
        for (int j = 0; j < FDIM; ++j) f[j] = fdg[(size_t)e * FDIM + j];
        f[FDIM] = rij[e];
        float acc = ca[0];
#pragma unroll
        for (int j = 0; j < ADIM; ++j) acc += f[j] * wa[j];
        unsigned rec[8];
#pragma unroll
        for (int j = 0; j < 5; ++j)
            rec[j] = (unsigned)f2bf(f[2 * j]) | ((unsigned)f2bf(f[2 * j + 1]) << 16);
        rec[5] = __float_as_uint(acc);
        rec[6] = 0; rec[7] = 0;
        uint4* dst = (uint4*)(emsg + (size_t)e * 16);
        dst[0] = make_uint4(rec[0], rec[1], rec[2], rec[3]);
        dst[1] = make_uint4(rec[4], rec[5], rec[6], rec[7]);
        sue[e] = (sul[e] > 0) ? su[e] : 0;
    }
}

// ---------------------------------------------------------------------------
// GAT iter 1 (round-10 shape, measured 42us). One wave per node.
// ---------------------------------------------------------------------------
__global__ __launch_bounds__(256) void k_gat1(
    const int* __restrict__ sse, const int* __restrict__ bsc,
    const float* __restrict__ t1A, const unsigned short* __restrict__ tfp,
    const unsigned short* __restrict__ emsg,
    const float* __restrict__ W2, const float* __restrict__ c2,
    const float* __restrict__ W3, const float* __restrict__ c3,
    const float* __restrict__ va, const float* __restrict__ vb,
    unsigned short* __restrict__ hp2bf, float* __restrict__ t1B,
    float* __restrict__ t2B)
{
    int wave = threadIdx.x >> 6;
    int lane = threadIdx.x & 63;
    int n = blockIdx.x * 4 + wave;
    if (n == 0) {
        hp2bf[lane] = 0;
        if (lane == 0) { t1B[0] = 0.f; t2B[0] = 0.f; }
    }
    if (n >= N_NODES) return;

    int kidx = 0, ke = 0;
    float lg = NEG_INF_F;
    if (lane < K_NB) {
        kidx = sse[n * K_NB + lane];
        ke   = bsc[n * K_NB + lane];
        float g2 = __uint_as_float(*(const unsigned*)(emsg + (size_t)ke * 16 + 10));
        float p = t1A[kidx] + g2;
        p = (p > 0.f) ? p : 0.2f * p;      // leaky_relu(0.2)
        lg = (kidx == 0) ? NEG_INF_F : p;  // pad mask
    }

    unsigned wn_u[K_NB], wm_u[K_NB];
    int offr = (lane & 15) * 2;            // short index within 32B record
#pragma unroll
    for (int k = 0; k < K_NB; ++k) {
        const unsigned short* pk = tfp + (size_t)readlane_i(kidx, k) * 16;
        GLOAD_U16(wn_u[k], offr, pk);
    }
#pragma unroll
    for (int k = 0; k < K_NB; ++k) {
        const unsigned short* pe = emsg + (size_t)readlane_i(ke, k) * 16;
        GLOAD_U16(wm_u[k], offr, pe);
    }

    // softmax across the 16-lane group — overlaps the gathers
    float m = lg;
#pragma unroll
    for (int o = 8; o > 0; o >>= 1) m = fmaxf(m, __shfl_xor(m, o, 64));
    float ex = __expf(lg - m);
    float s = ex;
#pragma unroll
    for (int o = 8; o > 0; o >>= 1) s += __shfl_xor(s, o, 64);
    float alpha = ex / s;

    DRAIN16(wn_u);
    HOLD16(wm_u);

    float fr = 0.f, frm = 0.f, beta = 0.f;
#pragma unroll
    for (int k = 0; k < K_NB; ++k) {
        float ak = readlane_f(alpha, k);
        fr  += ak * bf2f(wn_u[k]);         // lanes 9..15 read record pad zeros
        frm += ak * bf2f(wm_u[k]);         // lanes >= ADIM garbage, never read
        beta += (readlane_i(kidx, k) > 0) ? ak : 0.f;
    }
    float acc = c2[lane] + beta * c3[lane];
#pragma unroll
    for (int j = 0; j < FDIM; ++j) acc += readlane_f(fr, j) * W3[j * H + lane];
#pragma unroll
    for (int j = 0; j < ADIM; ++j) acc += readlane_f(frm, j) * W2[j * H + lane];
    float o = (acc > 0.f) ? acc : expm1f(acc);   // elu
    hp2bf[(size_t)(n + 1) * H + lane] = f2bf(o);
    float ta = o * va[lane], tb = o * vb[lane];  // f32-exact logit scalars
#pragma unroll
    for (int q = 32; q > 0; q >>= 1) {
        ta += __shfl_xor(ta, q, 64);
        tb += __shfl_xor(tb, q, 64);
    }
    if (lane == 0) { t1B[n + 1] = ta; t2B[n + 1] = tb; }
}

// ---------------------------------------------------------------------------
// GAT iter 2 — FUSED gather + MFMA projection (round-14).
// 1024-thread blocks = 16 waves = 16 hp3 rows. Each wave computes its node's
// packed (gn,gm) K=128 bf16 row (exactly the round-13 gather code), stages it
// in LDS (stride-72 uints: ≤2-way bank aliasing on A-frag reads), barrier,
// then waves 0..3 run one 16-col strip of the verified round-13 MFMA GEMM:
//   hp3[16,64] = elu( A[16,128] @ Wint[128,64] )
// Saves the 25.6MB gnm round-trip + the k_proj launch.
// ---------------------------------------------------------------------------
__global__ __launch_bounds__(1024) void k_gat2(
    const int* __restrict__ sse, const int* __restrict__ bsc,
    const int* __restrict__ sue,
    const float* __restrict__ t1B, const float* __restrict__ t2B,
    const unsigned short* __restrict__ hp2bf,
    const unsigned short* __restrict__ WintT,
    float* __restrict__ hp3)
{
    __shared__ unsigned s_rows[16][72];    // 16 rows x 64 uints (stride 72)
    int wave = threadIdx.x >> 6;           // 0..15 = row within block
    int lane = threadIdx.x & 63;
    int row  = blockIdx.x * 16 + wave;     // hp3 row
    int n    = row - 1;                    // node index (row 0 = pad)

    float gn = 0.f, gm = 0.f;
    if (n >= 0 && n < N_NODES) {
        int kidx = 0, ksu = 0;
        float lg = NEG_INF_F;
        if (lane < K_NB) {
            kidx = sse[n * K_NB + lane];
            int ke = bsc[n * K_NB + lane];
            ksu = sue[ke];                 // row 0 = zero row for masked edges
            float p = t1B[kidx] + t2B[ksu];
            p = (p > 0.f) ? p : 0.2f * p;
            lg = (kidx == 0) ? NEG_INF_F : p;
        }

        unsigned wn_u[K_NB], wm_u[K_NB];
        int off = lane * 2;
#pragma unroll
        for (int k = 0; k < K_NB; ++k) {
            const unsigned short* pk = hp2bf + (size_t)readlane_i(kidx, k) * H;
            GLOAD_U16(wn_u[k], off, pk);
        }
#pragma unroll
        for (int k = 0; k < K_NB; ++k) {
            const unsigned short* ps = hp2bf + (size_t)readlane_i(ksu, k) * H;
            GLOAD_U16(wm_u[k], off, ps);
        }

        float m = lg;
#pragma unroll
        for (int o = 8; o > 0; o >>= 1) m = fmaxf(m, __shfl_xor(m, o, 64));
        float ex = __expf(lg - m);
        float s = ex;
#pragma unroll
        for (int o = 8; o > 0; o >>= 1) s += __shfl_xor(s, o, 64);
        float alpha = ex / s;

        DRAIN16(wn_u);
        HOLD16(wm_u);

#pragma unroll
        for (int k = 0; k < K_NB; ++k) {
            float ak = readlane_f(alpha, k);
            gn += ak * bf2f(wn_u[k]);
            gm += ak * bf2f(wm_u[k]);
        }
    }
    s_rows[wave][lane] = (unsigned)f2bf(gn) | ((unsigned)f2bf(gm) << 16);
    __syncthreads();

    if (wave < 4) {                        // wave t = column strip t*16..
        int t = wave;
        int m = lane & 15, q = lane >> 4;
        union UB { uint4 u; bf16x8 v; };
        bf16x8 bfr[4];
        const unsigned short* bp = WintT + (size_t)(t * 16 + m) * 128 + q * 8;
#pragma unroll
        for (int kk = 0; kk < 4; ++kk) {
            UB ub; ub.u = *(const uint4*)(bp + kk * 32);
            bfr[kk] = ub.v;
        }
        f32x4 acc = (f32x4){0.f, 0.f, 0.f, 0.f};
#pragma unroll
        for (int kk = 0; kk < 4; ++kk) {
            UB ua; ua.u = *(const uint4*)&s_rows[m][kk * 16 + q * 4];
            acc = __builtin_amdgcn_mfma_f32_16x16x32_bf16(ua.v, bfr[kk], acc, 0, 0, 0);
        }
        int row0 = blockIdx.x * 16;
#pragma unroll
        for (int r = 0; r < 4; ++r) {
            int rr = row0 + q * 4 + r;
            if (rr <= N_NODES) {
                float v = acc[r];
                hp3[(size_t)rr * H + t * 16 + m] = (v > 0.f) ? v : expm1f(v);
            }
        }
    }
}

// ---------------------------------------------------------------------------
// out[b] = sum_m hp3[l_scope[b,m]] — 48 raw asm gathers all in flight.
// ---------------------------------------------------------------------------
__global__ __launch_bounds__(256) void k_out(
    const int* __restrict__ l_scope, const float* __restrict__ hp,
    float* __restrict__ out)
{
    int wave = threadIdx.x >> 6;
    int lane = threadIdx.x & 63;
    int b = blockIdx.x * 4 + wave;
    if (b >= B_MOL) return;
    int idx48 = (lane < MAXM_M) ? l_scope[b * MAXM_M + lane] : 0;
    float v[MAXM_M];
    int off = lane * 4;
#pragma unroll
    for (int m = 0; m < MAXM_M; ++m) {
        const float* pm = hp + (size_t)readlane_i(idx48, m) * H;
        GLOAD_F32(v[m], off, pm);
    }
    asm volatile("s_waitcnt vmcnt(0)"
        : "+v"(v[0]), "+v"(v[1]), "+v"(v[2]), "+v"(v[3]),
          "+v"(v[4]), "+v"(v[5]), "+v"(v[6]), "+v"(v[7]),
          "+v"(v[8]), "+v"(v[9]), "+v"(v[10]), "+v"(v[11]),
          "+v"(v[12]), "+v"(v[13]), "+v"(v[14]), "+v"(v[15]));
    asm volatile(""
        : "+v"(v[16]), "+v"(v[17]), "+v"(v[18]), "+v"(v[19]),
          "+v"(v[20]), "+v"(v[21]), "+v"(v[22]), "+v"(v[23]),
          "+v"(v[24]), "+v"(v[25]), "+v"(v[26]), "+v"(v[27]),
          "+v"(v[28]), "+v"(v[29]), "+v"(v[30]), "+v"(v[31]));
    asm volatile(""
        : "+v"(v[32]), "+v"(v[33]), "+v"(v[34]), "+v"(v[35]),
          "+v"(v[36]), "+v"(v[37]), "+v"(v[38]), "+v"(v[39]),
          "+v"(v[40]), "+v"(v[41]), "+v"(v[42]), "+v"(v[43]),
          "+v"(v[44]), "+v"(v[45]), "+v"(v[46]), "+v"(v[47]));
    float acc = 0.f;
#pragma unroll
    for (int m = 0; m < MAXM_M; ++m) acc += v[m];
    out[b * H + lane] = acc;
}

extern "C" void kernel_launch(void* const* d_in, const int* in_sizes, int n_in,
                              void* d_out, int out_size, void* d_ws, size_t ws_size,
                              hipStream_t stream)
{
    const float* tf     = (const float*)d_in[0];
    const float* fdg    = (const float*)d_in[1];
    const float* rij    = (const float*)d_in[2];
    const int*   sse    = (const int*)d_in[3];
    const int*   bsc    = (const int*)d_in[4];
    const int*   lsc    = (const int*)d_in[5];
    const int*   su     = (const int*)d_in[6];
    const int*   sul    = (const int*)d_in[7];
    const float* W_emb  = (const float*)d_in[8];
    const float* b_emb  = (const float*)d_in[9];
    const float* W_dist = (const float*)d_in[10];
    const float* b_dist = (const float*)d_in[11];
    const float* W_gat  = (const float*)d_in[12];
    const float* Wm_gat = (const float*)d_in[13];
    const float* a_gat  = (const float*)d_in[14];
    float* out = (float*)d_out;

    char* base = (char*)d_ws;
    size_t off = 0;
    auto alloc = [&](size_t bytes) {
        char* p = base + off;
        off = (off + bytes + 255) & ~(size_t)255;
        return p;
    };
    float* W2   = (float*)alloc(640 * 4);
    float* c2   = (float*)alloc(64 * 4);
    float* W3   = (float*)alloc(640 * 4);
    float* c3   = (float*)alloc(64 * 4);
    float* wa   = (float*)alloc(16 * 4);
    float* ca   = (float*)alloc(16 * 4);
    float* va   = (float*)alloc(64 * 4);
    float* vb   = (float*)alloc(64 * 4);
    float* wv9  = (float*)alloc(16 * 4);
    float* cv   = (float*)alloc(16 * 4);
    unsigned short* WintT = (unsigned short*)alloc(64 * 128 * 2);
    float* t1A  = (float*)alloc((size_t)(N_NODES + 1) * 4);
    float* t1B  = (float*)alloc((size_t)(N_NODES + 1) * 4);
    float* t2B  = (float*)alloc((size_t)(N_NODES + 1) * 4);
    int*   sue  = (int*)alloc((size_t)E_EDGES * 4);
    unsigned short* tfp   = (unsigned short*)alloc((size_t)(N_NODES + 1) * 16 * 2);
    unsigned short* hp2bf = (unsigned short*)alloc((size_t)(N_NODES + 1) * H * 2);
    // emsg (25.6MB) and hp3 (12.8MB) alias: emsg dead before k_gat2 writes hp3
    char* big = alloc((size_t)E_EDGES * 32);
    unsigned short* emsg = (unsigned short*)big;
    float* hp3 = (float*)big;

    k_fold<<<dim3(1), dim3(256), 0, stream>>>(
        W_emb, b_emb, W_dist, b_dist, W_gat, Wm_gat, a_gat,
        W2, c2, W3, c3, wa, ca, va, vb, wv9, cv, WintT);

    k_pre<<<dim3(PRE_NODE_BLOCKS + EDGE_BLOCKS), dim3(256), 0, stream>>>(
        tf, fdg, rij, su, sul, wa, ca, wv9, cv, t1A, tfp, emsg, sue);

    k_gat1<<<dim3((N_NODES + 3) / 4), dim3(256), 0, stream>>>(
        sse, bsc, t1A, tfp, emsg, W2, c2, W3, c3, va, vb, hp2bf, t1B, t2B);

    k_gat2<<<dim3((N_NODES + 16) / 16), dim3(1024), 0, stream>>>(
        sse, bsc, sue, t1B, t2B, hp2bf, WintT, hp3);

    k_out<<<dim3(B_MOL / 4), dim3(256), 0, stream>>>(lsc, hp3, out);
}